// Round 1
// baseline (27625.269 us; speedup 1.0000x reference)
//
#include <hip/hip_runtime.h>
#include <hip/hip_bf16.h>

typedef unsigned short u16;
typedef __attribute__((ext_vector_type(8))) short short8;
typedef __attribute__((ext_vector_type(4))) float f32x4;
typedef __attribute__((ext_vector_type(4))) int int4v;

// Problem constants
// T=48, B=64, S=48, CTX=1024, H=1024, E=512, V=32000; steps TS=47
#define TS 47
#define NB 64
#define NS 48
#define NCTX 1024
#define NH 1024
#define NE 512
#define NV 32000

// ---------------- embedding: yemb[t,b,:] = emb_W[y[t,b],:] * (y!=0) ----------------
__global__ __launch_bounds__(256) void k_embed(const int* __restrict__ y,
                                               const float* __restrict__ embW,
                                               float* __restrict__ yemb) {
    int idx = blockIdx.x * 256 + threadIdx.x;      // < 47*64*512
    int e = idx & (NE - 1);
    int tb = idx >> 9;                              // t*64+b, t<47
    int yv = y[tb];
    yemb[idx] = yv ? embW[yv * NE + e] : 0.f;
}

// ---------------- ctx mean over S ----------------
__global__ __launch_bounds__(256) void k_mean(const float* __restrict__ ctx,
                                              float* __restrict__ out) {
    int idx = blockIdx.x * 256 + threadIdx.x;      // b*1024+c, 65536 total
    float s = 0.f;
    for (int si = 0; si < NS; ++si) s += ctx[si * (NB * NCTX) + idx];
    out[idx] = s * (1.f / 48.f);
}

// ---------------- generic 64x64 fp32 tiled GEMM (ctx_proj only; dims divide evenly) ----------------
__global__ __launch_bounds__(256) void k_gemm64(const float* __restrict__ A,
                                                const float* __restrict__ B,
                                                float* __restrict__ C,
                                                int M, int N, int K) {
    __shared__ float As[16][68];   // [k][m], padded
    __shared__ float Bs[16][64];   // [k][n]
    int tid = threadIdx.x, tx = tid & 15, ty = tid >> 4;
    int m0 = blockIdx.y * 64, n0 = blockIdx.x * 64;
    float acc[4][4] = {};
    for (int k0 = 0; k0 < K; k0 += 16) {
        __syncthreads();
#pragma unroll
        for (int i = 0; i < 4; ++i) {
            int e = tid + i * 256;
            int r = e >> 4, c = e & 15;
            As[c][r] = A[(size_t)(m0 + r) * K + k0 + c];
            int r2 = e >> 6, c2 = e & 63;
            Bs[r2][c2] = B[(size_t)(k0 + r2) * N + n0 + c2];
        }
        __syncthreads();
#pragma unroll
        for (int kk = 0; kk < 16; ++kk) {
            float4 av = *(const float4*)&As[kk][ty * 4];
            float4 bv = *(const float4*)&Bs[kk][tx * 4];
            float a4[4] = {av.x, av.y, av.z, av.w};
            float b4[4] = {bv.x, bv.y, bv.z, bv.w};
#pragma unroll
            for (int i = 0; i < 4; ++i)
#pragma unroll
                for (int j = 0; j < 4; ++j) acc[i][j] += a4[i] * b4[j];
        }
    }
#pragma unroll
    for (int i = 0; i < 4; ++i)
#pragma unroll
        for (int j = 0; j < 4; ++j)
            C[(size_t)(m0 + ty * 4 + i) * N + n0 + tx * 4 + j] = acc[i][j];
}

// ---------------- skinny GEMM: out(64xN) = x(64xK) @ W(KxN) (+bias, opt tanh) ----------------
__global__ __launch_bounds__(256) void k_skinny(const float* __restrict__ x, int K,
                                                const float* __restrict__ W, int N,
                                                const float* __restrict__ bias, int act,
                                                float* __restrict__ out) {
    __shared__ float xs[64 * 16];
    __shared__ float ws[16 * 8];
    int tid = threadIdx.x, tx = tid & 7, ty = tid >> 3;  // ty: 0..31 -> rows 2ty,2ty+1
    int j0 = blockIdx.x * 8;
    float acc[2] = {0.f, 0.f};
    for (int k0 = 0; k0 < K; k0 += 16) {
        __syncthreads();
#pragma unroll
        for (int i = 0; i < 4; ++i) {
            int e = tid + i * 256;
            int r = e >> 4, c = e & 15;
            xs[r * 16 + c] = x[r * K + k0 + c];
        }
        if (tid < 128) {
            int r = tid >> 3, c = tid & 7;
            ws[tid] = W[(size_t)(k0 + r) * N + j0 + c];
        }
        __syncthreads();
#pragma unroll
        for (int kk = 0; kk < 16; ++kk) {
            float w = ws[kk * 8 + tx];
            acc[0] += xs[(ty * 2) * 16 + kk] * w;
            acc[1] += xs[(ty * 2 + 1) * 16 + kk] * w;
        }
    }
#pragma unroll
    for (int i = 0; i < 2; ++i) {
        int b = ty * 2 + i, j = j0 + tx;
        float v = acc[i] + (bias ? bias[j] : 0.f);
        if (act) v = tanhf(v);
        out[b * N + j] = v;
    }
}

// ---------------- fused GRU: hout = GRU(x, hprev) ----------------
__global__ __launch_bounds__(256) void k_gru(const float* __restrict__ x, int Kx,
                                             const float* __restrict__ Wih,
                                             const float* __restrict__ hprev,
                                             const float* __restrict__ Whh,
                                             const float* __restrict__ bih,
                                             const float* __restrict__ bhh,
                                             float* __restrict__ hout) {
    __shared__ float xs[64 * 16];
    __shared__ float wsh[3][16 * 8];
    int tid = threadIdx.x, tx = tid & 7, ty = tid >> 3;
    int j0 = blockIdx.x * 8;
    float accI[3][2] = {};
    float accH[3][2] = {};
    // phase 1: x @ Wih (3 gate column blocks)
    for (int k0 = 0; k0 < Kx; k0 += 16) {
        __syncthreads();
#pragma unroll
        for (int i = 0; i < 4; ++i) {
            int e = tid + i * 256;
            int r = e >> 4, c = e & 15;
            xs[r * 16 + c] = x[r * Kx + k0 + c];
        }
        for (int e = tid; e < 384; e += 256) {
            int g = e >> 7, ee = e & 127;
            int r = ee >> 3, c = ee & 7;
            wsh[g][r * 8 + c] = Wih[(size_t)(k0 + r) * (3 * NH) + g * NH + j0 + c];
        }
        __syncthreads();
#pragma unroll
        for (int kk = 0; kk < 16; ++kk) {
            float w0 = wsh[0][kk * 8 + tx], w1 = wsh[1][kk * 8 + tx], w2 = wsh[2][kk * 8 + tx];
#pragma unroll
            for (int i = 0; i < 2; ++i) {
                float a = xs[(ty * 2 + i) * 16 + kk];
                accI[0][i] += a * w0; accI[1][i] += a * w1; accI[2][i] += a * w2;
            }
        }
    }
    // phase 2: h @ Whh
    for (int k0 = 0; k0 < NH; k0 += 16) {
        __syncthreads();
#pragma unroll
        for (int i = 0; i < 4; ++i) {
            int e = tid + i * 256;
            int r = e >> 4, c = e & 15;
            xs[r * 16 + c] = hprev[r * NH + k0 + c];
        }
        for (int e = tid; e < 384; e += 256) {
            int g = e >> 7, ee = e & 127;
            int r = ee >> 3, c = ee & 7;
            wsh[g][r * 8 + c] = Whh[(size_t)(k0 + r) * (3 * NH) + g * NH + j0 + c];
        }
        __syncthreads();
#pragma unroll
        for (int kk = 0; kk < 16; ++kk) {
            float w0 = wsh[0][kk * 8 + tx], w1 = wsh[1][kk * 8 + tx], w2 = wsh[2][kk * 8 + tx];
#pragma unroll
            for (int i = 0; i < 2; ++i) {
                float a = xs[(ty * 2 + i) * 16 + kk];
                accH[0][i] += a * w0; accH[1][i] += a * w1; accH[2][i] += a * w2;
            }
        }
    }
#pragma unroll
    for (int i = 0; i < 2; ++i) {
        int b = ty * 2 + i, j = j0 + tx;
        float ir = accI[0][i] + bih[j];
        float iz = accI[1][i] + bih[NH + j];
        float ig = accI[2][i] + bih[2 * NH + j];
        float hr = accH[0][i] + bhh[j];
        float hz = accH[1][i] + bhh[NH + j];
        float hg = accH[2][i] + bhh[2 * NH + j];
        float r = 1.f / (1.f + __expf(-(ir + hr)));
        float zz = 1.f / (1.f + __expf(-(iz + hz)));
        float n = tanhf(ig + r * hg);
        float hp = hprev[b * NH + j];
        hout[b * NH + j] = (1.f - zz) * n + zz * hp;
    }
}

// ---------------- fused attention: scores -> softmax(S) -> z ----------------
__global__ __launch_bounds__(256) void k_attn(const float* __restrict__ ctxproj,
                                              const float* __restrict__ q,
                                              const float* __restrict__ mlpW,
                                              const float* __restrict__ ctx,
                                              float* __restrict__ z) {
    __shared__ float sc[64];
    int b = blockIdx.x, tid = threadIdx.x, lane = tid & 63, w = tid >> 6;
    const float* qb = q + b * NCTX;
    for (int s = w; s < NS; s += 4) {
        const float* cp = ctxproj + (size_t)(s * NB + b) * NCTX;
        float acc = 0.f;
        for (int c = lane; c < NCTX; c += 64) acc += tanhf(cp[c] + qb[c]) * mlpW[c];
#pragma unroll
        for (int off = 32; off > 0; off >>= 1) acc += __shfl_down(acc, off);
        if (lane == 0) sc[s] = acc;
    }
    __syncthreads();
    if (tid < 64) {
        float v = (tid < NS) ? sc[tid] : -3.4e38f;
        float m = v;
#pragma unroll
        for (int off = 32; off > 0; off >>= 1) m = fmaxf(m, __shfl_down(m, off));
        m = __shfl(m, 0);
        float ev = (tid < NS) ? __expf(v - m) : 0.f;
        float ssum = ev;
#pragma unroll
        for (int off = 32; off > 0; off >>= 1) ssum += __shfl_down(ssum, off);
        ssum = __shfl(ssum, 0);
        if (tid < NS) sc[tid] = ev / ssum;
    }
    __syncthreads();
    for (int c = tid; c < NCTX; c += 256) {
        float acc = 0.f;
#pragma unroll
        for (int s = 0; s < NS; ++s) acc += sc[s] * ctx[(size_t)(s * NB + b) * NCTX + c];
        z[b * NCTX + c] = acc;
    }
}

// ---------------- fp32 -> bf16 convert ----------------
__global__ __launch_bounds__(256) void k_f2bf(const float* __restrict__ in,
                                              u16* __restrict__ out, int n) {
    int i = blockIdx.x * 256 + threadIdx.x;
    if (i < n) {
        __hip_bfloat16 b = __float2bfloat16(in[i]);
        out[i] = *reinterpret_cast<u16*>(&b);
    }
}

// ---------------- transpose + convert: W[512][32000] -> Wt[32000][512] bf16 ----------------
__global__ void k_transpose_bf(const float* __restrict__ W, u16* __restrict__ Wt) {
    __shared__ float tile[32][33];
    int v0 = blockIdx.x * 32, e0 = blockIdx.y * 32;
    int tx = threadIdx.x, ty = threadIdx.y;  // (32,8)
#pragma unroll
    for (int i = 0; i < 4; ++i)
        tile[ty + 8 * i][tx] = W[(size_t)(e0 + ty + 8 * i) * NV + v0 + tx];
    __syncthreads();
#pragma unroll
    for (int i = 0; i < 4; ++i) {
        float val = tile[tx][ty + 8 * i];
        __hip_bfloat16 b = __float2bfloat16(val);
        Wt[(size_t)(v0 + ty + 8 * i) * NE + e0 + tx] = *reinterpret_cast<u16*>(&b);
    }
}

// ---------------- bf16 MFMA GEMM: C(MxN) = A(MxK) @ Bt(NxK)^T + bias ----------------
__global__ __launch_bounds__(256) void k_mfma_gemm(const u16* __restrict__ Abf,
                                                   const u16* __restrict__ Btbf,
                                                   const float* __restrict__ bias,
                                                   float* __restrict__ C,
                                                   int M, int N, int K) {
    constexpr int LD = 40;  // padded bf16 row stride (32 + 8)
    __shared__ u16 As[64 * LD];
    __shared__ u16 Bs[128 * LD];
    const int tid = threadIdx.x, lane = tid & 63, wid = tid >> 6;
    const int wm = wid >> 1, wn = wid & 1;           // 2x2 waves
    const int m0 = blockIdx.y * 64, n0 = blockIdx.x * 128;
    const int kg = (lane >> 4) * 8, rl = lane & 15;
    const int arow = tid >> 2, akk = (tid & 3) << 3;
    f32x4 acc[2][4] = {};
    for (int k0 = 0; k0 < K; k0 += 32) {
        __syncthreads();
        *(int4v*)&As[arow * LD + akk] = *(const int4v*)&Abf[(size_t)(m0 + arow) * K + k0 + akk];
#pragma unroll
        for (int p = 0; p < 2; ++p) {
            int brow = p * 64 + arow;
            *(int4v*)&Bs[brow * LD + akk] = *(const int4v*)&Btbf[(size_t)(n0 + brow) * K + k0 + akk];
        }
        __syncthreads();
        short8 af[2], bfv[4];
#pragma unroll
        for (int mi = 0; mi < 2; ++mi)
            af[mi] = *(const short8*)&As[(wm * 32 + mi * 16 + rl) * LD + kg];
#pragma unroll
        for (int ni = 0; ni < 4; ++ni)
            bfv[ni] = *(const short8*)&Bs[(wn * 64 + ni * 16 + rl) * LD + kg];
#pragma unroll
        for (int mi = 0; mi < 2; ++mi)
#pragma unroll
            for (int ni = 0; ni < 4; ++ni)
                acc[mi][ni] = __builtin_amdgcn_mfma_f32_16x16x32_bf16(af[mi], bfv[ni], acc[mi][ni], 0, 0, 0);
    }
#pragma unroll
    for (int mi = 0; mi < 2; ++mi) {
#pragma unroll
        for (int ni = 0; ni < 4; ++ni) {
            int col = n0 + wn * 64 + ni * 16 + rl;
            float bv = bias[col];
#pragma unroll
            for (int j = 0; j < 4; ++j) {
                int row = m0 + wm * 32 + mi * 16 + (lane >> 4) * 4 + j;
                C[(size_t)row * N + col] = acc[mi][ni][j] + bv;
            }
        }
    }
}

// ---------------- per-row online logsumexp (rows of 32000) ----------------
__global__ __launch_bounds__(256) void k_rowstat(const float* __restrict__ P,
                                                 float* __restrict__ lse) {
    __shared__ float sm[256], ss[256];
    int r = blockIdx.x;
    const float* row = P + (size_t)r * NV;
    float m = -3.4e38f, s = 0.f;
    for (int i = threadIdx.x; i < NV; i += 256) {
        float v = row[i];
        float nm = fmaxf(m, v);
        s = s * __expf(m - nm) + __expf(v - nm);
        m = nm;
    }
    sm[threadIdx.x] = m; ss[threadIdx.x] = s;
    __syncthreads();
    for (int off = 128; off > 0; off >>= 1) {
        if (threadIdx.x < off) {
            float m2 = sm[threadIdx.x + off], s2 = ss[threadIdx.x + off];
            float m1 = sm[threadIdx.x], s1 = ss[threadIdx.x];
            float nm = fmaxf(m1, m2);
            sm[threadIdx.x] = nm;
            ss[threadIdx.x] = s1 * __expf(m1 - nm) + s2 * __expf(m2 - nm);
        }
        __syncthreads();
    }
    if (threadIdx.x == 0) lse[r] = sm[0] + __logf(ss[0]);
}

// ---------------- in-place log_softmax finalize ----------------
__global__ __launch_bounds__(256) void k_finalize(float* __restrict__ P,
                                                  const float* __restrict__ lse) {
    int r = blockIdx.y;
    int c = blockIdx.x * 256 + threadIdx.x;
    P[(size_t)r * NV + c] -= lse[r];
}

// ---------------- masked NLL sum -> out[0] ----------------
__global__ __launch_bounds__(256) void k_loss(const float* __restrict__ logp,
                                              const int* __restrict__ y,
                                              float* __restrict__ out0) {
    __shared__ float red[256];
    float acc = 0.f;
    for (int r = threadIdx.x; r < TS * NB; r += 256) {
        int tgt = y[NB + r];  // y[1:] flattened
        if (tgt != 0) acc -= logp[(size_t)r * NV + tgt];
    }
    red[threadIdx.x] = acc;
    __syncthreads();
    for (int off = 128; off > 0; off >>= 1) {
        if (threadIdx.x < off) red[threadIdx.x] += red[threadIdx.x + off];
        __syncthreads();
    }
    if (threadIdx.x == 0) out0[0] = red[0];
}

extern "C" void kernel_launch(void* const* d_in, const int* in_sizes, int n_in,
                              void* d_out, int out_size, void* d_ws, size_t ws_size,
                              hipStream_t stream) {
    (void)in_sizes; (void)n_in; (void)out_size; (void)ws_size;
    const int*   y        = (const int*)d_in[0];
    const float* ctx      = (const float*)d_in[1];
    const float* embW     = (const float*)d_in[2];
    const float* ctx2ctxW = (const float*)d_in[3];
    const float* hid2ctxW = (const float*)d_in[4];
    const float* mlpW     = (const float*)d_in[5];
    const float* decInitW = (const float*)d_in[6];
    const float* decInitB = (const float*)d_in[7];
    const float* d0Wih    = (const float*)d_in[8];
    const float* d0Whh    = (const float*)d_in[9];
    const float* d0bih    = (const float*)d_in[10];
    const float* d0bhh    = (const float*)d_in[11];
    const float* d1Wih    = (const float*)d_in[12];
    const float* d1Whh    = (const float*)d_in[13];
    const float* d1bih    = (const float*)d_in[14];
    const float* d1bhh    = (const float*)d_in[15];
    const float* h2oW     = (const float*)d_in[16];
    const float* h2oB     = (const float*)d_in[17];
    const float* o2pW     = (const float*)d_in[18];
    const float* o2pB     = (const float*)d_in[19];

    float* out = (float*)d_out;

    char* wsBase = (char*)d_ws;
    size_t off = 0;
    auto carve = [&](size_t bytes) -> char* {
        char* p = wsBase + off;
        off += (bytes + 255) & ~(size_t)255;
        return p;
    };
    float* yemb    = (float*)carve((size_t)TS * NB * NE * 4);     // 47*64*512
    float* ctxproj = (float*)carve((size_t)NS * NB * NCTX * 4);   // 48*64*1024
    float* cmean   = (float*)carve((size_t)NB * NCTX * 4);
    float* h       = (float*)carve((size_t)NB * NH * 4);
    float* h1      = (float*)carve((size_t)NB * NH * 4);
    float* q       = (float*)carve((size_t)NB * NCTX * 4);
    float* zb      = (float*)carve((size_t)NB * NCTX * 4);
    float* logits  = (float*)carve((size_t)TS * NB * NE * 4);
    float* lse     = (float*)carve((size_t)TS * NB * 4);
    u16*   Abf     = (u16*)carve((size_t)TS * NB * NE * 2);
    u16*   Btbf    = (u16*)carve((size_t)NV * NE * 2);

    // ---- precompute (parallel) ----
    k_embed<<<(TS * NB * NE) / 256, 256, 0, stream>>>(y, embW, yemb);
    k_mean<<<(NB * NCTX) / 256, 256, 0, stream>>>(ctx, cmean);
    k_skinny<<<NH / 8, 256, 0, stream>>>(cmean, NCTX, decInitW, NH, decInitB, 1, h);
    k_gemm64<<<dim3(NCTX / 64, (NS * NB) / 64), 256, 0, stream>>>(ctx, ctx2ctxW, ctxproj,
                                                                  NS * NB, NCTX, NCTX);
    k_transpose_bf<<<dim3(NV / 32, NE / 32), dim3(32, 8), 0, stream>>>(o2pW, Btbf);

    // ---- sequential scan ----
    for (int t = 0; t < TS; ++t) {
        k_gru<<<NH / 8, 256, 0, stream>>>(yemb + (size_t)t * NB * NE, NE, d0Wih,
                                          h, d0Whh, d0bih, d0bhh, h1);
        k_skinny<<<NCTX / 8, 256, 0, stream>>>(h1, NH, hid2ctxW, NCTX, nullptr, 0, q);
        k_attn<<<NB, 256, 0, stream>>>(ctxproj, q, mlpW, ctx, zb);
        k_gru<<<NH / 8, 256, 0, stream>>>(zb, NCTX, d1Wih, h1, d1Whh, d1bih, d1bhh, h);
        k_skinny<<<NE / 8, 256, 0, stream>>>(h, NH, h2oW, NE, h2oB, 1,
                                             logits + (size_t)t * NB * NE);
    }

    // ---- batched vocab projection + log_softmax + loss ----
    k_f2bf<<<(TS * NB * NE + 255) / 256, 256, 0, stream>>>(logits, Abf, TS * NB * NE);
    k_mfma_gemm<<<dim3(NV / 128, (TS * NB) / 64), 256, 0, stream>>>(Abf, Btbf, o2pB, out + 1,
                                                                    TS * NB, NV, NE);
    k_rowstat<<<TS * NB, 256, 0, stream>>>(out + 1, lse);
    k_finalize<<<dim3(NV / 256, TS * NB), 256, 0, stream>>>(out + 1, lse);
    k_loss<<<1, 256, 0, stream>>>(out + 1, y, out);
}